// Round 1
// baseline (362.369 us; speedup 1.0000x reference)
//
#include <hip/hip_runtime.h>
#include <math.h>

// Problem constants (match reference.py)
#define HS_D       1024   // input_size
#define HS_MAXLEN  24     // max Huffman path depth

// One block (256 thr = 4 waves) per example.
// Wave w handles path steps l = w, w+4, w+8, ... (<6 each).
// Lane layout for the 1024-dim dot: lane reads float4 at index j*64+lane,
// j=0..3  -> fully coalesced 16B/lane loads for both x and W rows.
__global__ __launch_bounds__(256) void hsm_loss_kernel(
    const float* __restrict__ x,      // [N_EX, D]
    const float* __restrict__ W,      // [N_DEC, D]
    const int*   __restrict__ t,      // [N_EX]
    const int*   __restrict__ paths,  // [V, MAX_LEN]
    const float* __restrict__ codes,  // [V, MAX_LEN]
    const int*   __restrict__ lens,   // [V]
    float*       __restrict__ out)    // [1]
{
    const int n    = blockIdx.x;
    const int tid  = threadIdx.x;
    const int wave = tid >> 6;
    const int lane = tid & 63;

    const int leaf = t[n];          // wave-uniform -> s_load
    const int L    = lens[leaf];    // wave-uniform

    // Load this lane's fragment of x[n] once (16 floats = 4 x float4).
    const float4* x4 = (const float4*)(x + (size_t)n * HS_D);
    float4 xf[4];
#pragma unroll
    for (int j = 0; j < 4; ++j)
        xf[j] = x4[j * 64 + lane];

    float local = 0.0f;

    for (int l = wave; l < L; l += 4) {
        const int   node = paths[leaf * HS_MAXLEN + l];  // wave-uniform
        const float c    = codes[leaf * HS_MAXLEN + l];  // wave-uniform

        const float4* w4 = (const float4*)(W + (size_t)node * HS_D);
        float dot = 0.0f;
#pragma unroll
        for (int j = 0; j < 4; ++j) {
            const float4 wf = w4[j * 64 + lane];
            dot += xf[j].x * wf.x + xf[j].y * wf.y
                 + xf[j].z * wf.z + xf[j].w * wf.w;
        }

        // 64-lane wave reduction
#pragma unroll
        for (int off = 32; off > 0; off >>= 1)
            dot += __shfl_down(dot, off);

        if (lane == 0) {
            const float z = -c * dot;
            // stable softplus(z) = max(z,0) + log1p(exp(-|z|))
            local += fmaxf(z, 0.0f) + log1pf(expf(-fabsf(z)));
        }
    }

    __shared__ float s[4];
    if (lane == 0) s[wave] = local;
    __syncthreads();
    if (tid == 0) {
        const float blocksum = s[0] + s[1] + s[2] + s[3];
        atomicAdd(out, blocksum);
    }
}

extern "C" void kernel_launch(void* const* d_in, const int* in_sizes, int n_in,
                              void* d_out, int out_size, void* d_ws, size_t ws_size,
                              hipStream_t stream) {
    const float* x     = (const float*)d_in[0];
    const float* W     = (const float*)d_in[1];
    const int*   t     = (const int*)  d_in[2];
    const int*   paths = (const int*)  d_in[3];
    const float* codes = (const float*)d_in[4];
    const int*   lens  = (const int*)  d_in[5];
    float* out = (float*)d_out;

    const int n_ex = in_sizes[2];  // t has N_EX elements

    // d_out is poisoned with 0xAA before every timed launch -> zero it.
    hipMemsetAsync(out, 0, sizeof(float), stream);

    hsm_loss_kernel<<<n_ex, 256, 0, stream>>>(x, W, t, paths, codes, lens, out);
}